// Round 8
// baseline (239.507 us; speedup 1.0000x reference)
//
#include <hip/hip_runtime.h>
#include <math.h>

// Problem constants (fixed by the reference setup_inputs()).
#define TT 3
#define NN 50000
#define DD 64
#define EE 800000
#define LL 2
#define NK3 (NN * TT)              // 150000 (row,tau) CSR keys
#define NB3 ((NK3 + 255) / 256)    // 586 scan blocks
#define CH 96                      // edge-walk LDS chunk (>= typical node degree)

typedef _Float16 h4 __attribute__((ext_vector_type(4)));
typedef float f4 __attribute__((ext_vector_type(4)));

// ---------------------------------------------------------------------------
// k_small: O(T*D) edge-feature transforms for BOTH layers + f16 B matrices.
// ---------------------------------------------------------------------------
__global__ void k_small(const float* __restrict__ ef0,
                        const float* __restrict__ tg,   // [L,T,D]
                        const float* __restrict__ wr,   // [L,D,D]
                        const float* __restrict__ we,   // [L,D,D]
                        const float* __restrict__ thj,  // [L,T,D]
                        float* __restrict__ rg,         // [L*T*T]
                        float* __restrict__ sig,        // [L*T*D]
                        _Float16* __restrict__ bf)      // [L*80*64] Bt[c][k]
{
    __shared__ float ef_l[TT * DD];
    __shared__ float efn[TT * DD];
    int tid = threadIdx.x;
    // precompute f16 B = [we^T cols | thj rows | 0] for both layers
    for (int l = 0; l < LL; ++l)
        for (int idx = tid; idx < 80 * 64; idx += 256) {
            int c = idx >> 6, k = idx & 63;
            float v = 0.f;
            if (c < 64) v = we[l * 4096 + k * 64 + c];
            else if (c < 67) v = thj[l * 192 + (c - 64) * 64 + k];
            bf[l * 5120 + idx] = (_Float16)v;
        }
    if (tid < TT * DD) ef_l[tid] = ef0[tid];
    __syncthreads();
    for (int layer = 0; layer < LL; ++layer) {
        if (tid < TT * TT) {
            int t = tid / TT, tau = tid % TT;
            float s = 0.f;
            #pragma unroll
            for (int k = 0; k < DD; ++k)
                s += ef_l[tau * DD + k] * tg[layer * TT * DD + t * DD + k];
            rg[layer * TT * TT + tid] = s;
        }
        if (tid < TT * DD) {
            int tau = tid / DD, d = tid % DD;
            float s = 0.f;
            #pragma unroll
            for (int k = 0; k < DD; ++k)
                s += ef_l[tau * DD + k] * wr[layer * DD * DD + k * DD + d];
            efn[tid] = s;
            sig[layer * TT * DD + tid] = 1.f / (1.f + expf(-s));
        }
        __syncthreads();
        if (tid < TT * DD) ef_l[tid] = fmaxf(efn[tid], 0.f);
        __syncthreads();
    }
}

// ---------------------------------------------------------------------------
// CSR over (row, etype) keys.
// ---------------------------------------------------------------------------
__global__ void k_count3(const int* __restrict__ row, const int* __restrict__ et,
                         int* __restrict__ counts)
{
    int e = blockIdx.x * 256 + threadIdx.x;
    if (e < EE) atomicAdd(&counts[row[e] * 3 + et[e]], 1);
}

__global__ void k_bsum(const int* __restrict__ counts, int* __restrict__ bsum)
{
    __shared__ int red[256];
    int i = blockIdx.x * 256 + threadIdx.x;
    red[threadIdx.x] = (i < NK3) ? counts[i] : 0;
    __syncthreads();
    for (int off = 128; off >= 1; off >>= 1) {
        if (threadIdx.x < off) red[threadIdx.x] += red[threadIdx.x + off];
        __syncthreads();
    }
    if (threadIdx.x == 0) bsum[blockIdx.x] = red[0];
}

// emit with inlined bsum-prefix (k_bscan merged away): each block re-derives
// its exclusive block prefix from the raw bsum array (343k extra L2 reads,
// free) then emits per-key offsets.
__global__ void k_emit2(const int* __restrict__ counts,
                        const int* __restrict__ bsum,   // raw per-block sums
                        int* __restrict__ csroff,
                        int* __restrict__ cursor)
{
    __shared__ int s[256];
    __shared__ int bpre_s;
    int b = blockIdx.x, tid = threadIdx.x;
    // exclusive prefix of bsum[0..b-1]
    int pp = 0;
    for (int i = tid; i < b; i += 256) pp += bsum[i];
    s[tid] = pp;
    __syncthreads();
    for (int off = 128; off >= 1; off >>= 1) {
        if (tid < off) s[tid] += s[tid + off];
        __syncthreads();
    }
    if (tid == 0) bpre_s = s[0];
    __syncthreads();
    int bpre = bpre_s;
    int idx = b * 256 + tid;
    int c = (idx < NK3) ? counts[idx] : 0;
    s[tid] = c;
    __syncthreads();
    for (int off = 1; off < 256; off <<= 1) {
        int u = (tid >= off) ? s[tid - off] : 0;
        __syncthreads();
        s[tid] += u;
        __syncthreads();
    }
    if (idx < NK3) {
        int o = bpre + s[tid] - c;
        csroff[idx] = o;
        cursor[idx] = o;
    }
    if (b == NB3 - 1 && tid == 255) csroff[NK3] = bpre + s[255];
}

__global__ void k_scatter3(const int* __restrict__ row, const int* __restrict__ col,
                           const int* __restrict__ et,
                           int* __restrict__ cursor,
                           unsigned short* __restrict__ pk)
{
    int e = blockIdx.x * 256 + threadIdx.x;
    if (e < EE) {
        int key = row[e] * 3 + et[e];
        int pos = atomicAdd(&cursor[key], 1);
        pk[pos] = (unsigned short)col[e];   // col < 50000 < 2^16
    }
}

// ---------------------------------------------------------------------------
// k_mm0: MFMA f16 GEMM for layer 0: C[N,80] = x[N,64] @ Bf0.
//   cols 0..63 -> hw0 [n][64] f16; cols 64..66 -> ahj0[n*4+t].
// ---------------------------------------------------------------------------
__global__ __launch_bounds__(256) void k_mm0(
    const float* __restrict__ x,      // [N,64]
    const _Float16* __restrict__ Bf,  // [80*64] Bt[c][k] f16
    _Float16* __restrict__ hw,        // [N,64]
    float* __restrict__ ahj)          // [N,4]
{
    __shared__ _Float16 Ah[64][68];
    __shared__ _Float16 Bt[80][68];
    int tid = threadIdx.x;
    long rbase = (long)blockIdx.x * 64;

    #pragma unroll
    for (int it = 0; it < 4; ++it) {
        int flat = (tid + it * 256) * 4;
        int r = flat >> 6, k = flat & 63;
        h4 hv = {};
        if (rbase + r < NN) {
            float4 v = *(const float4*)&x[(rbase + r) * 64 + k];
            hv = h4{ (_Float16)v.x, (_Float16)v.y, (_Float16)v.z, (_Float16)v.w };
        }
        *(h4*)&Ah[r][k] = hv;
    }
    for (int e4 = tid; e4 < 80 * 64 / 4; e4 += 256) {
        int idx = e4 * 4;
        *(h4*)&Bt[idx >> 6][idx & 63] = *(const h4*)&Bf[idx];
    }
    __syncthreads();

    int wid = tid >> 6, lane = tid & 63;
    int r16 = lane & 15, kq = lane >> 4;
    f4 acc[5] = {};
    #pragma unroll
    for (int ks = 0; ks < 4; ++ks) {
        int k0 = ks * 16 + kq * 4;
        h4 a = *(h4*)&Ah[wid * 16 + r16][k0];
        #pragma unroll
        for (int ct = 0; ct < 5; ++ct) {
            h4 b = *(h4*)&Bt[ct * 16 + r16][k0];
            acc[ct] = __builtin_amdgcn_mfma_f32_16x16x16f16(a, b, acc[ct], 0, 0, 0);
        }
    }
    #pragma unroll
    for (int j = 0; j < 4; ++j) {
        long g = rbase + wid * 16 + kq * 4 + j;
        if (g < NN) {
            #pragma unroll
            for (int ct = 0; ct < 4; ++ct)
                hw[g * 64 + ct * 16 + r16] = (_Float16)acc[ct][j];
            if (r16 < 3) ahj[g * 4 + r16] = acc[4][j];
        }
    }
}

// ---------------------------------------------------------------------------
// k_fused: layer-0 edge aggregation + residual + LAYER-1 GEMM in one kernel.
// 512 thr = 8 waves; 64 nodes/block. Each wave walks 8 nodes' edges (gather
// hw0, flat unroll x4, tau packed in bits 26-27), forms h1 = x + relu(o) as
// f16 rows in LDS (row = node_local*3 + t), then the block runs the layer-1
// MFMA GEMM on the 192-row tile -> hw1 [n][3][64] + ahj1. h1 never touches
// global memory (saves 38.4 MB of traffic vs separate k_edge0 + k_mm1).
// ---------------------------------------------------------------------------
__global__ __launch_bounds__(512) void k_fused(
    const int* __restrict__ off3,            // [NK3+1]
    const unsigned short* __restrict__ pk,   // [E]
    const float* __restrict__ rg_l,          // [9] layer-0 r[t][tau]
    const float* __restrict__ sig_l,         // [3*64] layer-0 (tau,d)
    const float* __restrict__ ahj0,          // [N*4] layer-0
    const _Float16* __restrict__ hw0,        // [N*64]
    const float* __restrict__ x,             // [N*64]
    const _Float16* __restrict__ Bf1,        // [80*64] layer-1 B table
    _Float16* __restrict__ hw1,              // [N*3*64]
    float* __restrict__ ahj1)                // [N*4]
{
    __shared__ _Float16 A[192][68];
    __shared__ _Float16 Bt[80][68];
    __shared__ uint4 ent[8][CH];
    int tid = threadIdx.x, wid = tid >> 6, lane = tid & 63;
    int nbase = blockIdx.x * 64;

    for (int e4 = tid; e4 < 80 * 64 / 4; e4 += 512) {
        int idx = e4 * 4;
        *(h4*)&Bt[idx >> 6][idx & 63] = *(const h4*)&Bf1[idx];
    }

    float r00 = rg_l[0], r01 = rg_l[1], r02 = rg_l[2];
    float r10 = rg_l[3], r11 = rg_l[4], r12 = rg_l[5];
    float r20 = rg_l[6], r21 = rg_l[7], r22 = rg_l[8];
    float sg0 = sig_l[lane], sg1 = sig_l[64 + lane], sg2 = sig_l[128 + lane];
    const char* hwb = (const char*)hw0 + (size_t)lane * 2;
    uint4* myent = ent[wid];

    for (int i = 0; i < 8; ++i) {
        int nl = wid * 8 + i;
        int n = nbase + nl;
        float acc0 = 0.f, acc1 = 0.f, acc2 = 0.f;
        float ps0 = 0.f, ps1 = 0.f, ps2 = 0.f;
        int s0 = 0, s3 = 0;
        if (n < NN) {
            int b3 = n * 3;
            s0 = off3[b3];
            int s1 = off3[b3 + 1], s2 = off3[b3 + 2];
            s3 = off3[b3 + 3];
            for (int base = s0; base < s3; base += CH) {
                int cnt = s3 - base; if (cnt > CH) cnt = CH;
                for (int jj = lane; jj < cnt; jj += 64) {
                    int ei = base + jj;
                    int c = pk[ei];
                    int tau = (ei >= s1) + (ei >= s2);
                    float4 aj = *(const float4*)&ahj0[c * 4];
                    float g0 = (tau == 0) ? r00 : ((tau == 1) ? r01 : r02);
                    float g1 = (tau == 0) ? r10 : ((tau == 1) ? r11 : r12);
                    float g2 = (tau == 0) ? r20 : ((tau == 1) ? r21 : r22);
                    float p0 = __expf(g0 + aj.x);
                    float p1 = __expf(g1 + aj.y);
                    float p2 = __expf(g2 + aj.z);
                    ps0 += p0; ps1 += p1; ps2 += p2;
                    myent[jj] = make_uint4(((unsigned)c * 128u) | ((unsigned)tau << 26),
                                           __float_as_uint(p0), __float_as_uint(p1),
                                           __float_as_uint(p2));
                }
                asm volatile("s_waitcnt lgkmcnt(0)" ::: "memory");
#define AGG(J) { uint4 e = myent[J];                                           \
        unsigned ta = e.x >> 26;                                               \
        float sg = (ta == 0) ? sg0 : ((ta == 1) ? sg1 : sg2);                  \
        float sv = sg * (float)*(const _Float16*)(hwb + (e.x & 0x03FFFFFFu));  \
        acc0 = fmaf(__uint_as_float(e.y), sv, acc0);                           \
        acc1 = fmaf(__uint_as_float(e.z), sv, acc1);                           \
        acc2 = fmaf(__uint_as_float(e.w), sv, acc2); }
                int j = 0;
                for (; j + 4 <= cnt; j += 4) { AGG(j) AGG(j + 1) AGG(j + 2) AGG(j + 3) }
                for (; j < cnt; ++j) { AGG(j) }
#undef AGG
                asm volatile("s_waitcnt lgkmcnt(0)" ::: "memory");
            }
        }
        #pragma unroll
        for (int off = 32; off >= 1; off >>= 1) {
            ps0 += __shfl_xor(ps0, off);
            ps1 += __shfl_xor(ps1, off);
            ps2 += __shfl_xor(ps2, off);
        }
        float o0 = 0.f, o1 = 0.f, o2 = 0.f;
        if (s3 > s0) { o0 = acc0 / ps0; o1 = acc1 / ps1; o2 = acc2 / ps2; }
        float xv = (n < NN) ? x[(size_t)n * 64 + lane] : 0.f;
        A[nl * 3 + 0][lane] = (_Float16)(xv + fmaxf(o0, 0.f));
        A[nl * 3 + 1][lane] = (_Float16)(xv + fmaxf(o1, 0.f));
        A[nl * 3 + 2][lane] = (_Float16)(xv + fmaxf(o2, 0.f));
    }
    __syncthreads();

    // layer-1 GEMM on the 192-row h1 tile: 12 strips of 16 rows x 80 cols
    int r16 = lane & 15, kq = lane >> 4;
    for (int strip = wid; strip < 12; strip += 8) {
        f4 acc[5] = {};
        #pragma unroll
        for (int ks = 0; ks < 4; ++ks) {
            int k0 = ks * 16 + kq * 4;
            h4 a = *(h4*)&A[strip * 16 + r16][k0];
            #pragma unroll
            for (int ct = 0; ct < 5; ++ct) {
                h4 b = *(h4*)&Bt[ct * 16 + r16][k0];
                acc[ct] = __builtin_amdgcn_mfma_f32_16x16x16f16(a, b, acc[ct], 0, 0, 0);
            }
        }
        #pragma unroll
        for (int j = 0; j < 4; ++j) {
            int g = strip * 16 + kq * 4 + j;   // row in [0,192)
            int nl = g / 3, t = g - nl * 3;
            int n = nbase + nl;
            if (n < NN) {
                #pragma unroll
                for (int ct = 0; ct < 4; ++ct)
                    hw1[((size_t)n * 3 + t) * 64 + ct * 16 + r16] = (_Float16)acc[ct][j];
                if (r16 == t) ahj1[n * 4 + t] = acc[4][j];
            }
        }
    }
}

// ---------------------------------------------------------------------------
// k_edge1: layer-1 aggregation (R5 byte-minimal form). One node per wave,
// all 3 t's; hw1 [n][3][64] -> 3 f16 loads at +0/+128/+256 from one base;
// flat loop, tau packed in bits 26-27, unroll x4 for outstanding loads.
// ---------------------------------------------------------------------------
__global__ __launch_bounds__(256) void k_edge1(
    const int* __restrict__ off3,            // [NK3+1]
    const unsigned short* __restrict__ pk,   // [E]
    const float* __restrict__ rg_l,          // [9] layer-1
    const float* __restrict__ sig_l,         // [3*64] layer-1
    const float* __restrict__ ahj4,          // [N*4] layer-1
    const _Float16* __restrict__ hw,         // [N*3*64]
    float* __restrict__ outf)                // [3,N,64] f32
{
    __shared__ uint4 ent[4][CH];
    int wid = threadIdx.x >> 6, lane = threadIdx.x & 63;
    int n = blockIdx.x * 4 + wid;            // NN % 4 == 0, no tail
    int b3 = n * 3;
    int s0 = off3[b3], s1 = off3[b3 + 1], s2 = off3[b3 + 2], s3 = off3[b3 + 3];
    float r00 = rg_l[0], r01 = rg_l[1], r02 = rg_l[2];
    float r10 = rg_l[3], r11 = rg_l[4], r12 = rg_l[5];
    float r20 = rg_l[6], r21 = rg_l[7], r22 = rg_l[8];
    float sg0 = sig_l[lane], sg1 = sig_l[64 + lane], sg2 = sig_l[128 + lane];
    const char* hwb = (const char*)hw + (size_t)lane * 2;
    uint4* myent = ent[wid];
    float acc0 = 0.f, acc1 = 0.f, acc2 = 0.f;
    float ps0 = 0.f, ps1 = 0.f, ps2 = 0.f;

    for (int base = s0; base < s3; base += CH) {
        int cnt = s3 - base; if (cnt > CH) cnt = CH;
        for (int jj = lane; jj < cnt; jj += 64) {
            int ei = base + jj;
            int c = pk[ei];
            int tau = (ei >= s1) + (ei >= s2);
            float4 aj = *(const float4*)&ahj4[c * 4];
            float g0 = (tau == 0) ? r00 : ((tau == 1) ? r01 : r02);
            float g1 = (tau == 0) ? r10 : ((tau == 1) ? r11 : r12);
            float g2 = (tau == 0) ? r20 : ((tau == 1) ? r21 : r22);
            float p0 = __expf(g0 + aj.x);
            float p1 = __expf(g1 + aj.y);
            float p2 = __expf(g2 + aj.z);
            ps0 += p0; ps1 += p1; ps2 += p2;
            myent[jj] = make_uint4(((unsigned)c * 384u) | ((unsigned)tau << 26),
                                   __float_as_uint(p0), __float_as_uint(p1),
                                   __float_as_uint(p2));
        }
        asm volatile("s_waitcnt lgkmcnt(0)" ::: "memory");

#define AGG(J) { uint4 e = myent[J];                                           \
        unsigned ta = e.x >> 26;                                               \
        float sg = (ta == 0) ? sg0 : ((ta == 1) ? sg1 : sg2);                  \
        const char* ptr = hwb + (e.x & 0x03FFFFFFu);                           \
        float v0 = (float)*(const _Float16*)(ptr);                             \
        float v1 = (float)*(const _Float16*)(ptr + 128);                       \
        float v2 = (float)*(const _Float16*)(ptr + 256);                       \
        acc0 = fmaf(__uint_as_float(e.y), sg * v0, acc0);                      \
        acc1 = fmaf(__uint_as_float(e.z), sg * v1, acc1);                      \
        acc2 = fmaf(__uint_as_float(e.w), sg * v2, acc2); }

        int j = 0;
        for (; j + 4 <= cnt; j += 4) { AGG(j) AGG(j + 1) AGG(j + 2) AGG(j + 3) }
        for (; j < cnt; ++j) { AGG(j) }
#undef AGG
        asm volatile("s_waitcnt lgkmcnt(0)" ::: "memory");
    }
    #pragma unroll
    for (int off = 32; off >= 1; off >>= 1) {
        ps0 += __shfl_xor(ps0, off);
        ps1 += __shfl_xor(ps1, off);
        ps2 += __shfl_xor(ps2, off);
    }
    float o0 = 0.f, o1 = 0.f, o2 = 0.f;
    if (s3 > s0) { o0 = acc0 / ps0; o1 = acc1 / ps1; o2 = acc2 / ps2; }
    size_t oi = (size_t)n * 64 + lane;
    outf[oi]                       = o0;
    outf[oi + (size_t)NN * 64]     = o1;
    outf[oi + (size_t)2 * NN * 64] = o2;
}

// ---------------------------------------------------------------------------
extern "C" void kernel_launch(void* const* d_in, const int* in_sizes, int n_in,
                              void* d_out, int out_size, void* d_ws, size_t ws_size,
                              hipStream_t stream)
{
    const float* x   = (const float*)d_in[0];
    const int*   ei  = (const int*)d_in[1];
    const int*   row = ei;
    const int*   col = ei + EE;
    const int*   et  = (const int*)d_in[2];
    const float* ef  = (const float*)d_in[3];
    const float* tg  = (const float*)d_in[4];
    // d_in[5] = theta_hi: cancels in scatter-softmax (constant per group)
    const float* thj = (const float*)d_in[6];
    const float* we  = (const float*)d_in[7];
    const float* wr  = (const float*)d_in[8];
    float* out = (float*)d_out;

    // workspace layout
    _Float16* hw1 = (_Float16*)d_ws;                      // N*3*64
    _Float16* hw0 = hw1 + (size_t)NN * 3 * 64;            // N*64
    float* ahj0 = (float*)(hw0 + (size_t)NN * 64);        // N*4
    float* ahj1 = ahj0 + (size_t)NN * 4;                  // N*4
    float* rg   = ahj1 + (size_t)NN * 4;                  // L*9
    float* sig  = rg + LL * 9;                            // L*192
    _Float16* bfB = (_Float16*)(sig + LL * 192);          // L*80*64 f16
    int* counts3 = (int*)(bfB + LL * 5120);               // NK3
    int* csroff3 = counts3 + NK3;                         // NK3+1
    int* cursor3 = csroff3 + NK3 + 1;                     // NK3
    int* bsum    = cursor3 + NK3;                         // NB3+1
    unsigned short* csrpk = (unsigned short*)(bsum + NB3 + 1);  // E

    hipMemsetAsync(counts3, 0, NK3 * sizeof(int), stream);
    k_small<<<1, 256, 0, stream>>>(ef, tg, wr, we, thj, rg, sig, bfB);
    k_count3<<<(EE + 255) / 256, 256, 0, stream>>>(row, et, counts3);
    k_bsum<<<NB3, 256, 0, stream>>>(counts3, bsum);
    k_emit2<<<NB3, 256, 0, stream>>>(counts3, bsum, csroff3, cursor3);
    k_scatter3<<<(EE + 255) / 256, 256, 0, stream>>>(row, col, et, cursor3, csrpk);

    // layer 0 GEMM: hw0 = x@we0 (f16), ahj0
    k_mm0<<<(NN + 63) / 64, 256, 0, stream>>>(x, bfB, hw0, ahj0);
    // fused: layer-0 aggregation + residual + layer-1 GEMM (h1 never hits HBM)
    k_fused<<<(NN + 63) / 64, 512, 0, stream>>>(csroff3, csrpk, rg, sig,
                                                ahj0, hw0, x, bfB + 5120,
                                                hw1, ahj1);
    // layer-1 aggregation -> final f32 output
    k_edge1<<<NN / 4, 256, 0, stream>>>(csroff3, csrpk, rg + 9, sig + 192,
                                        ahj1, hw1, out);
}

// Round 9
// 179.545 us; speedup vs baseline: 1.3340x; 1.3340x over previous
//
#include <hip/hip_runtime.h>
#include <math.h>

// Problem constants (fixed by the reference setup_inputs()).
#define TT 3
#define NN 50000
#define DD 64
#define EE 800000
#define LL 2
#define NK3 (NN * TT)              // 150000 (row,tau) CSR keys
#define NB3 ((NK3 + 255) / 256)    // 586 scan blocks
#define CH 96                      // edge-walk LDS chunk (>= typical node degree)

typedef _Float16 h4 __attribute__((ext_vector_type(4)));
typedef float f4 __attribute__((ext_vector_type(4)));

// ---------------------------------------------------------------------------
// k_small: O(T*D) edge-feature transforms for BOTH layers + f16 B matrices.
// ---------------------------------------------------------------------------
__global__ void k_small(const float* __restrict__ ef0,
                        const float* __restrict__ tg,   // [L,T,D]
                        const float* __restrict__ wr,   // [L,D,D]
                        const float* __restrict__ we,   // [L,D,D]
                        const float* __restrict__ thj,  // [L,T,D]
                        float* __restrict__ rg,         // [L*T*T]
                        float* __restrict__ sig,        // [L*T*D]
                        _Float16* __restrict__ bf)      // [L*80*64] Bt[c][k]
{
    __shared__ float ef_l[TT * DD];
    __shared__ float efn[TT * DD];
    int tid = threadIdx.x;
    for (int l = 0; l < LL; ++l)
        for (int idx = tid; idx < 80 * 64; idx += 256) {
            int c = idx >> 6, k = idx & 63;
            float v = 0.f;
            if (c < 64) v = we[l * 4096 + k * 64 + c];
            else if (c < 67) v = thj[l * 192 + (c - 64) * 64 + k];
            bf[l * 5120 + idx] = (_Float16)v;
        }
    if (tid < TT * DD) ef_l[tid] = ef0[tid];
    __syncthreads();
    for (int layer = 0; layer < LL; ++layer) {
        if (tid < TT * TT) {
            int t = tid / TT, tau = tid % TT;
            float s = 0.f;
            #pragma unroll
            for (int k = 0; k < DD; ++k)
                s += ef_l[tau * DD + k] * tg[layer * TT * DD + t * DD + k];
            rg[layer * TT * TT + tid] = s;
        }
        if (tid < TT * DD) {
            int tau = tid / DD, d = tid % DD;
            float s = 0.f;
            #pragma unroll
            for (int k = 0; k < DD; ++k)
                s += ef_l[tau * DD + k] * wr[layer * DD * DD + k * DD + d];
            efn[tid] = s;
            sig[layer * TT * DD + tid] = 1.f / (1.f + expf(-s));
        }
        __syncthreads();
        if (tid < TT * DD) ef_l[tid] = fmaxf(efn[tid], 0.f);
        __syncthreads();
    }
}

// ---------------------------------------------------------------------------
// CSR build. count3r keeps the atomic's old value as the edge's RANK within
// its (row,etype) key -> scatter needs NO atomics (half the device-scope
// atomic traffic of the old count+cursor scheme).
// ---------------------------------------------------------------------------
__global__ void k_count3r(const int* __restrict__ row, const int* __restrict__ et,
                          int* __restrict__ counts, unsigned* __restrict__ keyrank)
{
    int e = blockIdx.x * 256 + threadIdx.x;
    if (e < EE) {
        int key = row[e] * 3 + et[e];
        int r = atomicAdd(&counts[key], 1);
        keyrank[e] = ((unsigned)key << 14) | (unsigned)r;   // rank < 16384 (max deg ~40)
    }
}

__global__ void k_bsum(const int* __restrict__ counts, int* __restrict__ bsum)
{
    __shared__ int red[256];
    int i = blockIdx.x * 256 + threadIdx.x;
    red[threadIdx.x] = (i < NK3) ? counts[i] : 0;
    __syncthreads();
    for (int off = 128; off >= 1; off >>= 1) {
        if (threadIdx.x < off) red[threadIdx.x] += red[threadIdx.x + off];
        __syncthreads();
    }
    if (threadIdx.x == 0) bsum[blockIdx.x] = red[0];
}

// emit with inlined bsum-prefix: each block re-derives its exclusive block
// prefix from the raw per-block sums, then emits per-key CSR offsets.
__global__ void k_emit2(const int* __restrict__ counts,
                        const int* __restrict__ bsum,
                        int* __restrict__ csroff)
{
    __shared__ int s[256];
    __shared__ int bpre_s;
    int b = blockIdx.x, tid = threadIdx.x;
    int pp = 0;
    for (int i = tid; i < b; i += 256) pp += bsum[i];
    s[tid] = pp;
    __syncthreads();
    for (int off = 128; off >= 1; off >>= 1) {
        if (tid < off) s[tid] += s[tid + off];
        __syncthreads();
    }
    if (tid == 0) bpre_s = s[0];
    __syncthreads();
    int bpre = bpre_s;
    int idx = b * 256 + tid;
    int c = (idx < NK3) ? counts[idx] : 0;
    s[tid] = c;
    __syncthreads();
    for (int off = 1; off < 256; off <<= 1) {
        int u = (tid >= off) ? s[tid - off] : 0;
        __syncthreads();
        s[tid] += u;
        __syncthreads();
    }
    if (idx < NK3) csroff[idx] = bpre + s[tid] - c;
    if (b == NB3 - 1 && tid == 255) csroff[NK3] = bpre + s[255];
}

// atomic-free scatter: pos = csroff[key] + rank.
__global__ void k_scatter3r(const unsigned* __restrict__ keyrank,
                            const int* __restrict__ col,
                            const int* __restrict__ csroff,
                            unsigned short* __restrict__ pk)
{
    int e = blockIdx.x * 256 + threadIdx.x;
    if (e < EE) {
        unsigned kr = keyrank[e];
        int pos = csroff[kr >> 14] + (int)(kr & 16383u);
        pk[pos] = (unsigned short)col[e];   // col < 50000 < 2^16
    }
}

// ---------------------------------------------------------------------------
// k_mm0: MFMA f16 GEMM for layer 0: C[N,80] = x[N,64] @ Bf0.
//   cols 0..63 -> hw0 [n][64] f16; cols 64..66 -> ahj0[n*4+t].
// ---------------------------------------------------------------------------
__global__ __launch_bounds__(256) void k_mm0(
    const float* __restrict__ x,
    const _Float16* __restrict__ Bf,
    _Float16* __restrict__ hw,
    float* __restrict__ ahj)
{
    __shared__ _Float16 Ah[64][68];
    __shared__ _Float16 Bt[80][68];
    int tid = threadIdx.x;
    long rbase = (long)blockIdx.x * 64;

    #pragma unroll
    for (int it = 0; it < 4; ++it) {
        int flat = (tid + it * 256) * 4;
        int r = flat >> 6, k = flat & 63;
        h4 hv = {};
        if (rbase + r < NN) {
            float4 v = *(const float4*)&x[(rbase + r) * 64 + k];
            hv = h4{ (_Float16)v.x, (_Float16)v.y, (_Float16)v.z, (_Float16)v.w };
        }
        *(h4*)&Ah[r][k] = hv;
    }
    for (int e4 = tid; e4 < 80 * 64 / 4; e4 += 256) {
        int idx = e4 * 4;
        *(h4*)&Bt[idx >> 6][idx & 63] = *(const h4*)&Bf[idx];
    }
    __syncthreads();

    int wid = tid >> 6, lane = tid & 63;
    int r16 = lane & 15, kq = lane >> 4;
    f4 acc[5] = {};
    #pragma unroll
    for (int ks = 0; ks < 4; ++ks) {
        int k0 = ks * 16 + kq * 4;
        h4 a = *(h4*)&Ah[wid * 16 + r16][k0];
        #pragma unroll
        for (int ct = 0; ct < 5; ++ct) {
            h4 b = *(h4*)&Bt[ct * 16 + r16][k0];
            acc[ct] = __builtin_amdgcn_mfma_f32_16x16x16f16(a, b, acc[ct], 0, 0, 0);
        }
    }
    #pragma unroll
    for (int j = 0; j < 4; ++j) {
        long g = rbase + wid * 16 + kq * 4 + j;
        if (g < NN) {
            #pragma unroll
            for (int ct = 0; ct < 4; ++ct)
                hw[g * 64 + ct * 16 + r16] = (_Float16)acc[ct][j];
            if (r16 < 3) ahj[g * 4 + r16] = acc[4][j];
        }
    }
}

// ---------------------------------------------------------------------------
// k_mm1: layer-1 GEMM. Reads h1 (f16, staged in d_out, rows = t*N+n),
// writes hw1 [n][3][64] f16 + ahj1 [n][4].
// ---------------------------------------------------------------------------
__global__ __launch_bounds__(256) void k_mm1(
    const _Float16* __restrict__ h,
    const _Float16* __restrict__ Bf,
    _Float16* __restrict__ hw,
    float* __restrict__ ahj)
{
    __shared__ _Float16 Ah[64][68];
    __shared__ _Float16 Bt[80][68];
    int tid = threadIdx.x;
    long rbase = (long)blockIdx.x * 64;

    #pragma unroll
    for (int it = 0; it < 4; ++it) {
        int flat = (tid + it * 256) * 4;
        int r = flat >> 6, k = flat & 63;
        h4 hv = {};
        if (rbase + r < NK3) hv = *(const h4*)&h[(rbase + r) * 64 + k];
        *(h4*)&Ah[r][k] = hv;
    }
    for (int e4 = tid; e4 < 80 * 64 / 4; e4 += 256) {
        int idx = e4 * 4;
        *(h4*)&Bt[idx >> 6][idx & 63] = *(const h4*)&Bf[idx];
    }
    __syncthreads();

    int wid = tid >> 6, lane = tid & 63;
    int r16 = lane & 15, kq = lane >> 4;
    f4 acc[5] = {};
    #pragma unroll
    for (int ks = 0; ks < 4; ++ks) {
        int k0 = ks * 16 + kq * 4;
        h4 a = *(h4*)&Ah[wid * 16 + r16][k0];
        #pragma unroll
        for (int ct = 0; ct < 5; ++ct) {
            h4 b = *(h4*)&Bt[ct * 16 + r16][k0];
            acc[ct] = __builtin_amdgcn_mfma_f32_16x16x16f16(a, b, acc[ct], 0, 0, 0);
        }
    }
    #pragma unroll
    for (int j = 0; j < 4; ++j) {
        long g = rbase + wid * 16 + kq * 4 + j;
        if (g < NK3) {
            int t = (g >= 2L * NN) ? 2 : (g >= NN ? 1 : 0);
            long n = g - (long)t * NN;
            #pragma unroll
            for (int ct = 0; ct < 4; ++ct)
                hw[((size_t)n * 3 + t) * 64 + ct * 16 + r16] = (_Float16)acc[ct][j];
            if (r16 == t) ahj[n * 4 + t] = acc[4][j];
        }
    }
}

// ---------------------------------------------------------------------------
// k_edge0: layer-0 aggregation. One node per wave, all 3 t's; hw0 [N][64]
// is t-invariant -> 1 gather feeds 3 accumulators. Flat loop, tau packed in
// bits 26-27, unroll x4 for outstanding loads. Writes h1 = x+relu(o) as f16.
// ---------------------------------------------------------------------------
__global__ __launch_bounds__(256) void k_edge0(
    const int* __restrict__ off3,
    const unsigned short* __restrict__ pk,
    const float* __restrict__ rg_l,          // [9] layer-0
    const float* __restrict__ sig_l,         // [3*64] layer-0
    const float* __restrict__ ahj4,          // [N*4] layer-0
    const _Float16* __restrict__ hw,         // [N*64]
    const float* __restrict__ x,
    _Float16* __restrict__ outh)             // h1 f16 [3,N,64]
{
    __shared__ uint4 ent[4][CH];
    int wid = threadIdx.x >> 6, lane = threadIdx.x & 63;
    int n = blockIdx.x * 4 + wid;            // NN % 4 == 0
    int b3 = n * 3;
    int s0 = off3[b3], s1 = off3[b3 + 1], s2 = off3[b3 + 2], s3 = off3[b3 + 3];
    float r00 = rg_l[0], r01 = rg_l[1], r02 = rg_l[2];
    float r10 = rg_l[3], r11 = rg_l[4], r12 = rg_l[5];
    float r20 = rg_l[6], r21 = rg_l[7], r22 = rg_l[8];
    float sg0 = sig_l[lane], sg1 = sig_l[64 + lane], sg2 = sig_l[128 + lane];
    const char* hwb = (const char*)hw + (size_t)lane * 2;
    uint4* myent = ent[wid];
    float acc0 = 0.f, acc1 = 0.f, acc2 = 0.f;
    float ps0 = 0.f, ps1 = 0.f, ps2 = 0.f;

    for (int base = s0; base < s3; base += CH) {
        int cnt = s3 - base; if (cnt > CH) cnt = CH;
        for (int jj = lane; jj < cnt; jj += 64) {
            int ei = base + jj;
            int c = pk[ei];
            int tau = (ei >= s1) + (ei >= s2);
            float4 aj = *(const float4*)&ahj4[c * 4];
            float g0 = (tau == 0) ? r00 : ((tau == 1) ? r01 : r02);
            float g1 = (tau == 0) ? r10 : ((tau == 1) ? r11 : r12);
            float g2 = (tau == 0) ? r20 : ((tau == 1) ? r21 : r22);
            float p0 = __expf(g0 + aj.x);
            float p1 = __expf(g1 + aj.y);
            float p2 = __expf(g2 + aj.z);
            ps0 += p0; ps1 += p1; ps2 += p2;
            myent[jj] = make_uint4(((unsigned)c * 128u) | ((unsigned)tau << 26),
                                   __float_as_uint(p0), __float_as_uint(p1),
                                   __float_as_uint(p2));
        }
        asm volatile("s_waitcnt lgkmcnt(0)" ::: "memory");

#define AGG(J) { uint4 e = myent[J];                                           \
        unsigned ta = e.x >> 26;                                               \
        float sg = (ta == 0) ? sg0 : ((ta == 1) ? sg1 : sg2);                  \
        float sv = sg * (float)*(const _Float16*)(hwb + (e.x & 0x03FFFFFFu));  \
        acc0 = fmaf(__uint_as_float(e.y), sv, acc0);                           \
        acc1 = fmaf(__uint_as_float(e.z), sv, acc1);                           \
        acc2 = fmaf(__uint_as_float(e.w), sv, acc2); }
        int j = 0;
        for (; j + 4 <= cnt; j += 4) { AGG(j) AGG(j + 1) AGG(j + 2) AGG(j + 3) }
        for (; j < cnt; ++j) { AGG(j) }
#undef AGG
        asm volatile("s_waitcnt lgkmcnt(0)" ::: "memory");
    }
    #pragma unroll
    for (int off = 32; off >= 1; off >>= 1) {
        ps0 += __shfl_xor(ps0, off);
        ps1 += __shfl_xor(ps1, off);
        ps2 += __shfl_xor(ps2, off);
    }
    float o0 = 0.f, o1 = 0.f, o2 = 0.f;
    if (s3 > s0) { o0 = acc0 / ps0; o1 = acc1 / ps1; o2 = acc2 / ps2; }
    size_t oi = (size_t)n * 64 + lane;
    float xv = x[oi];
    outh[oi]                       = (_Float16)(xv + fmaxf(o0, 0.f));
    outh[oi + (size_t)NN * 64]     = (_Float16)(xv + fmaxf(o1, 0.f));
    outh[oi + (size_t)2 * NN * 64] = (_Float16)(xv + fmaxf(o2, 0.f));
}

// ---------------------------------------------------------------------------
// k_edge1: layer-1 aggregation (byte-minimal). hw1 [n][3][64] -> 3 f16 loads
// at +0/+128/+256 from one base; flat loop, unroll x4.
// ---------------------------------------------------------------------------
__global__ __launch_bounds__(256) void k_edge1(
    const int* __restrict__ off3,
    const unsigned short* __restrict__ pk,
    const float* __restrict__ rg_l,          // [9] layer-1
    const float* __restrict__ sig_l,         // [3*64] layer-1
    const float* __restrict__ ahj4,          // [N*4] layer-1
    const _Float16* __restrict__ hw,         // [N*3*64]
    float* __restrict__ outf)                // [3,N,64] f32
{
    __shared__ uint4 ent[4][CH];
    int wid = threadIdx.x >> 6, lane = threadIdx.x & 63;
    int n = blockIdx.x * 4 + wid;
    int b3 = n * 3;
    int s0 = off3[b3], s1 = off3[b3 + 1], s2 = off3[b3 + 2], s3 = off3[b3 + 3];
    float r00 = rg_l[0], r01 = rg_l[1], r02 = rg_l[2];
    float r10 = rg_l[3], r11 = rg_l[4], r12 = rg_l[5];
    float r20 = rg_l[6], r21 = rg_l[7], r22 = rg_l[8];
    float sg0 = sig_l[lane], sg1 = sig_l[64 + lane], sg2 = sig_l[128 + lane];
    const char* hwb = (const char*)hw + (size_t)lane * 2;
    uint4* myent = ent[wid];
    float acc0 = 0.f, acc1 = 0.f, acc2 = 0.f;
    float ps0 = 0.f, ps1 = 0.f, ps2 = 0.f;

    for (int base = s0; base < s3; base += CH) {
        int cnt = s3 - base; if (cnt > CH) cnt = CH;
        for (int jj = lane; jj < cnt; jj += 64) {
            int ei = base + jj;
            int c = pk[ei];
            int tau = (ei >= s1) + (ei >= s2);
            float4 aj = *(const float4*)&ahj4[c * 4];
            float g0 = (tau == 0) ? r00 : ((tau == 1) ? r01 : r02);
            float g1 = (tau == 0) ? r10 : ((tau == 1) ? r11 : r12);
            float g2 = (tau == 0) ? r20 : ((tau == 1) ? r21 : r22);
            float p0 = __expf(g0 + aj.x);
            float p1 = __expf(g1 + aj.y);
            float p2 = __expf(g2 + aj.z);
            ps0 += p0; ps1 += p1; ps2 += p2;
            myent[jj] = make_uint4(((unsigned)c * 384u) | ((unsigned)tau << 26),
                                   __float_as_uint(p0), __float_as_uint(p1),
                                   __float_as_uint(p2));
        }
        asm volatile("s_waitcnt lgkmcnt(0)" ::: "memory");

#define AGG(J) { uint4 e = myent[J];                                           \
        unsigned ta = e.x >> 26;                                               \
        float sg = (ta == 0) ? sg0 : ((ta == 1) ? sg1 : sg2);                  \
        const char* ptr = hwb + (e.x & 0x03FFFFFFu);                           \
        float v0 = (float)*(const _Float16*)(ptr);                             \
        float v1 = (float)*(const _Float16*)(ptr + 128);                       \
        float v2 = (float)*(const _Float16*)(ptr + 256);                       \
        acc0 = fmaf(__uint_as_float(e.y), sg * v0, acc0);                      \
        acc1 = fmaf(__uint_as_float(e.z), sg * v1, acc1);                      \
        acc2 = fmaf(__uint_as_float(e.w), sg * v2, acc2); }
        int j = 0;
        for (; j + 4 <= cnt; j += 4) { AGG(j) AGG(j + 1) AGG(j + 2) AGG(j + 3) }
        for (; j < cnt; ++j) { AGG(j) }
#undef AGG
        asm volatile("s_waitcnt lgkmcnt(0)" ::: "memory");
    }
    #pragma unroll
    for (int off = 32; off >= 1; off >>= 1) {
        ps0 += __shfl_xor(ps0, off);
        ps1 += __shfl_xor(ps1, off);
        ps2 += __shfl_xor(ps2, off);
    }
    float o0 = 0.f, o1 = 0.f, o2 = 0.f;
    if (s3 > s0) { o0 = acc0 / ps0; o1 = acc1 / ps1; o2 = acc2 / ps2; }
    size_t oi = (size_t)n * 64 + lane;
    outf[oi]                       = o0;
    outf[oi + (size_t)NN * 64]     = o1;
    outf[oi + (size_t)2 * NN * 64] = o2;
}

// ---------------------------------------------------------------------------
extern "C" void kernel_launch(void* const* d_in, const int* in_sizes, int n_in,
                              void* d_out, int out_size, void* d_ws, size_t ws_size,
                              hipStream_t stream)
{
    const float* x   = (const float*)d_in[0];
    const int*   ei  = (const int*)d_in[1];
    const int*   row = ei;
    const int*   col = ei + EE;
    const int*   et  = (const int*)d_in[2];
    const float* ef  = (const float*)d_in[3];
    const float* tg  = (const float*)d_in[4];
    // d_in[5] = theta_hi: cancels in scatter-softmax (constant per group)
    const float* thj = (const float*)d_in[6];
    const float* we  = (const float*)d_in[7];
    const float* wr  = (const float*)d_in[8];
    float* out = (float*)d_out;
    _Float16* h1h = (_Float16*)d_out;   // h1 staged as f16 in d_out

    // workspace layout
    _Float16* hw1 = (_Float16*)d_ws;                      // N*3*64
    _Float16* hw0 = hw1 + (size_t)NN * 3 * 64;            // N*64
    float* ahj0 = (float*)(hw0 + (size_t)NN * 64);        // N*4
    float* ahj1 = ahj0 + (size_t)NN * 4;                  // N*4
    float* rg   = ahj1 + (size_t)NN * 4;                  // L*9
    float* sig  = rg + LL * 9;                            // L*192
    _Float16* bfB = (_Float16*)(sig + LL * 192);          // L*80*64 f16
    int* counts3 = (int*)(bfB + LL * 5120);               // NK3
    int* csroff3 = counts3 + NK3;                         // NK3+1
    int* bsum    = csroff3 + NK3 + 1;                     // NB3
    unsigned* keyrank = (unsigned*)(bsum + NB3);          // E
    unsigned short* csrpk = (unsigned short*)(keyrank + EE);  // E

    hipMemsetAsync(counts3, 0, NK3 * sizeof(int), stream);
    k_small<<<1, 256, 0, stream>>>(ef, tg, wr, we, thj, rg, sig, bfB);
    k_count3r<<<(EE + 255) / 256, 256, 0, stream>>>(row, et, counts3, keyrank);
    k_bsum<<<NB3, 256, 0, stream>>>(counts3, bsum);
    k_emit2<<<NB3, 256, 0, stream>>>(counts3, bsum, csroff3);
    k_scatter3r<<<(EE + 255) / 256, 256, 0, stream>>>(keyrank, col, csroff3, csrpk);

    // layer 0 GEMM: hw0 = x@we0 (f16), ahj0
    k_mm0<<<(NN + 63) / 64, 256, 0, stream>>>(x, bfB, hw0, ahj0);
    // layer-0 aggregation -> h1 f16 staged in d_out
    k_edge0<<<NN / 4, 256, 0, stream>>>(csroff3, csrpk, rg, sig, ahj0, hw0,
                                        x, h1h);
    // layer-1 GEMM: hw1 = h1@we1 (f16, [n][3][64]), ahj1
    k_mm1<<<(NK3 + 63) / 64, 256, 0, stream>>>(h1h, bfB + 5120, hw1, ahj1);
    // layer-1 aggregation -> final f32 output
    k_edge1<<<NN / 4, 256, 0, stream>>>(csroff3, csrpk, rg + 9, sig + 192,
                                        ahj1, hw1, out);
}